// Round 9
// baseline (206.615 us; speedup 1.0000x reference)
//
#include <hip/hip_runtime.h>
#include <hip/hip_bf16.h>

typedef __bf16 bf16x8 __attribute__((ext_vector_type(8)));
typedef __bf16 bf16x4 __attribute__((ext_vector_type(4)));
typedef float floatx4 __attribute__((ext_vector_type(4)));
using bf16 = __hip_bfloat16;

#define S_    2048
#define NHEAD 16
#define LOG2E 1.4426950408889634f

// Async global->LDS DMA, 16 B per lane (lane i -> lds + i*16).
__device__ __forceinline__ void load_lds16(const bf16* g, void* lds) {
  __builtin_amdgcn_global_load_lds((const __attribute__((address_space(1))) void*)g,
                                   (__attribute__((address_space(3))) void*)lds, 16, 0, 0);
}

// ---------------------------------------------------------------------------
// Cast fp32 -> bf16, 4 elems/thread.
// ---------------------------------------------------------------------------
__global__ void cast_f32_bf16_kernel(const float* __restrict__ src, bf16* __restrict__ dst) {
  int i = (blockIdx.x * 256 + threadIdx.x) * 4;
  float4 v = *(const float4*)(src + i);
  bf16 o[4] = {__float2bfloat16(v.x), __float2bfloat16(v.y),
               __float2bfloat16(v.z), __float2bfloat16(v.w)};
  *(uint2*)(dst + i) = *(const uint2*)o;
}

// ---------------------------------------------------------------------------
// Transpose+cast weights: src fp32 [K=1024][N=1024] -> dst bf16 [N][K].
// ---------------------------------------------------------------------------
__global__ void transpose_w_kernel(const float* __restrict__ wq, const float* __restrict__ wk,
                                   const float* __restrict__ wv, const float* __restrict__ wo,
                                   bf16* __restrict__ wt_qkv, bf16* __restrict__ wt_o) {
  __shared__ bf16 tile[32][33];
  int mat = blockIdx.z;
  const float* src = (mat == 0) ? wq : (mat == 1) ? wk : (mat == 2) ? wv : wo;
  bf16* dst = (mat == 3) ? wt_o : wt_qkv + mat * 1024 * 1024;
  int tx = threadIdx.x, ty = threadIdx.y;
  int n0 = blockIdx.x * 32, k0 = blockIdx.y * 32;
#pragma unroll
  for (int j = 0; j < 32; j += 8)
    tile[ty + j][tx] = __float2bfloat16(src[(k0 + ty + j) * 1024 + n0 + tx]);
  __syncthreads();
#pragma unroll
  for (int j = 0; j < 32; j += 8)
    dst[(n0 + ty + j) * 1024 + k0 + tx] = tile[tx][ty + j];
}

// ---------------------------------------------------------------------------
// T5 bias LUT, PRE-SCALED by log2(e): tab[h*4096 + (delta+2048)].
// ---------------------------------------------------------------------------
__global__ void bias_table_kernel(const float* __restrict__ rel_bias, float* __restrict__ tab) {
  int idx = blockIdx.x * 256 + threadIdx.x;   // 16*4096 = 65536
  int h = idx >> 12, j = idx & 4095;
  int delta = j - 2048;                        // k - q
  int rb = (delta > 0) ? 16 : 0;
  int rpa = delta < 0 ? -delta : delta;
  int bsmall;
  if (rpa < 8) {
    bsmall = rpa;
  } else {
    int lg = 25 - __clz(rpa * rpa);
    bsmall = 8 + lg;
    if (bsmall > 15) bsmall = 15;
  }
  tab[idx] = rel_bias[(rb + bsmall) * 16 + h] * LOG2E;
}

// ---------------------------------------------------------------------------
// QKV GEMM, m97-style staging. Epilogue writes q head-major (qh[bh][s][64])
// and K/V directly in MFMA-fragment-major layouts (kf/vf).
// ---------------------------------------------------------------------------
__global__ __launch_bounds__(256) void gemm_qkv_kernel(const bf16* __restrict__ A,
                                                       const bf16* __restrict__ Bt,
                                                       bf16* __restrict__ qh,
                                                       bf16* __restrict__ kf,
                                                       bf16* __restrict__ vf) {
  const int K = 1024;
  __shared__ bf16 As[128 * 32];
  __shared__ bf16 Bs[128 * 32];
  int t = threadIdx.x;
  int m0 = blockIdx.y * 128, n0 = blockIdx.x * 128;
  int w = t >> 6, lane = t & 63, ln = lane & 15, quad = lane >> 4;
  int wr = w >> 1, wc = w & 1;
  floatx4 acc[4][4];
  floatx4 zero = {0.f, 0.f, 0.f, 0.f};
#pragma unroll
  for (int i = 0; i < 4; i++)
#pragma unroll
    for (int j = 0; j < 4; j++) acc[i][j] = zero;

  int r = t >> 2, c = (t & 3) * 8;
  const bf16* Ag = A + (long)(m0 + r) * K + c;
  const bf16* Bg = Bt + (long)(n0 + r) * K + c;
  char* ldsA0 = (char*)As + w * 1024;
  char* ldsA1 = ldsA0 + 4096;
  char* ldsB0 = (char*)Bs + w * 1024;
  char* ldsB1 = ldsB0 + 4096;

  for (int k0 = 0; k0 < K; k0 += 32) {
    load_lds16(Ag + k0, ldsA0);
    load_lds16(Ag + (long)64 * K + k0, ldsA1);
    load_lds16(Bg + k0, ldsB0);
    load_lds16(Bg + (long)64 * K + k0, ldsB1);
    __syncthreads();
    bf16x8 af[4], bfv[4];
#pragma unroll
    for (int i = 0; i < 4; i++)
      af[i] = *(const bf16x8*)&As[(wr * 64 + i * 16 + ln) * 32 + quad * 8];
#pragma unroll
    for (int j = 0; j < 4; j++)
      bfv[j] = *(const bf16x8*)&Bs[(wc * 64 + j * 16 + ln) * 32 + quad * 8];
#pragma unroll
    for (int i = 0; i < 4; i++)
#pragma unroll
      for (int j = 0; j < 4; j++)
        acc[i][j] = __builtin_amdgcn_mfma_f32_16x16x32_bf16(af[i], bfv[j], acc[i][j], 0, 0, 0);
    __syncthreads();
  }

  int nb = n0 + wc * 64;                        // 64-aligned column block
  int type = nb >> 10, h = (nb >> 6) & 15;
  int b = (m0 >> 11);
  int sl0 = (m0 & 2047) + wr * 64;
  long bhbase = (long)((b * 16 + h)) * 131072;

  if (type == 0) {
#pragma unroll
    for (int i = 0; i < 4; i++)
#pragma unroll
      for (int j = 0; j < 4; j++) {
        int d = j * 16 + ln;
#pragma unroll
        for (int rr = 0; rr < 4; rr++) {
          int s = sl0 + i * 16 + quad * 4 + rr;
          qh[bhbase + (long)s * 64 + d] = __float2bfloat16(acc[i][j][rr]);
        }
      }
  } else if (type == 1) {
#pragma unroll
    for (int i = 0; i < 4; i++)
#pragma unroll
      for (int j = 0; j < 4; j++) {
        int d = j * 16 + ln;
        int dpart = (d >> 5) * 512 + ((d >> 3) & 3) * 128 + (d & 7);
        int kb = (sl0 + i * 16) * 64;
#pragma unroll
        for (int rr = 0; rr < 4; rr++)
          kf[bhbase + kb + dpart + (quad * 4 + rr) * 8] = __float2bfloat16(acc[i][j][rr]);
      }
  } else {
#pragma unroll
    for (int i = 0; i < 4; i++)
#pragma unroll
      for (int j = 0; j < 4; j++) {
        int off = (sl0 + (i >> 1) * 32) * 64 + j * 512 +
                  ((quad >> 1) + ((i & 1) << 1)) * 128 + ln * 8 + (quad & 1) * 4;
        bf16x4 pk = {(__bf16)acc[i][j][0], (__bf16)acc[i][j][1],
                     (__bf16)acc[i][j][2], (__bf16)acc[i][j][3]};
        *(bf16x4*)(vf + bhbase + off) = pk;
      }
  }
}

// ---------------------------------------------------------------------------
// Flash attention, LDS-traffic-optimized. Grid (32 bh, 16 qblk), 4 waves x
// 32 q rows (2 q-groups share K/V -> LDS bytes per MFMA halved vs round 8).
// K: LDS double-buffered DMA (8KB/iter/block). V: register prefetch from
// global, one iteration ahead (no LDS cost; 4 waves share lines via L1).
// LDS = 16KB P + 2x8KB K = 32KB.
// ---------------------------------------------------------------------------
__global__ __launch_bounds__(256, 2) void attn_kernel(const bf16* __restrict__ qh,
                                                      const bf16* __restrict__ kf,
                                                      const bf16* __restrict__ vf,
                                                      const float* __restrict__ btab,
                                                      bf16* __restrict__ ctx) {
  __shared__ char PsRaw[4 * 4096];             // per-wave 4KB (2 groups x 2KB)
  __shared__ char Ks[2][8192];                 // K double buffer
  int t = threadIdx.x, w = t >> 6, lane = t & 63, ln = lane & 15, quad = lane >> 4;
  int bh = blockIdx.x, b = bh >> 4, h = bh & 15;
  int qw = blockIdx.y * 128 + w * 32;          // this wave's first q row

  const bf16* qbase = qh + (long)bh * S_ * 64;
  const bf16* kfb = kf + (long)bh * S_ * 64;
  const bf16* vfb = vf + (long)bh * S_ * 64;
  const float* bt = btab + h * 4096;
  char* myPs = PsRaw + w * 4096;
  int lbo = quad * 256 + ln * 16;              // lane byte offset inside 1KB frag
  int foff = quad * 128 + ln * 8;              // same, in elements

  // Q as B-operand: lane holds q = qw+g*16+ln, d = f*32+quad*8+j
  bf16x8 Qf[2][2];
#pragma unroll
  for (int g = 0; g < 2; g++) {
    const bf16* qr = qbase + (long)(qw + g * 16 + ln) * 64;
    Qf[g][0] = *(const bf16x8*)(qr + quad * 8);
    Qf[g][1] = *(const bf16x8*)(qr + 32 + quad * 8);
  }

  float cneg = bt[0], cpos = bt[4095];
  float l_acc[2] = {0.f, 0.f};
  floatx4 o[2][4];
  floatx4 zero = {0.f, 0.f, 0.f, 0.f};
#pragma unroll
  for (int g = 0; g < 2; g++)
#pragma unroll
    for (int dt = 0; dt < 4; dt++) o[g][dt] = zero;

  // stage K tile 0 into buf 0; preload V tile 0 into registers
  load_lds16(kfb + t * 8, Ks[0] + w * 1024);
  load_lds16(kfb + 2048 + t * 8, Ks[0] + 4096 + w * 1024);
  bf16x8 Vc[4][2], Vn[4][2];
#pragma unroll
  for (int f = 0; f < 2; f++)
#pragma unroll
    for (int dt = 0; dt < 4; dt++)
      Vc[dt][f] = *(const bf16x8*)(vfb + f * 2048 + dt * 512 + foff);

  int pb = 0;
  for (int k0 = 0; k0 < S_; k0 += 64) {
    __syncthreads();                           // K buf pb ready; prev reads done
    int kn = k0 + 64;
    if (kn < S_) {
      // issue next K DMA + next V register loads (consumed next iteration)
      const bf16* kg = kfb + (long)kn * 64 + t * 8;
      load_lds16(kg, Ks[pb ^ 1] + w * 1024);
      load_lds16(kg + 2048, Ks[pb ^ 1] + 4096 + w * 1024);
      const bf16* vp = vfb + (long)kn * 64;
#pragma unroll
      for (int f = 0; f < 2; f++)
#pragma unroll
        for (int dt = 0; dt < 4; dt++)
          Vn[dt][f] = *(const bf16x8*)(vp + f * 2048 + dt * 512 + foff);
    }

    const char* bK = Ks[pb];
    bf16x8 Kr[4][2];
#pragma unroll
    for (int tile = 0; tile < 4; tile++) {
      Kr[tile][0] = *(const bf16x8*)(bK + tile * 2048 + lbo);
      Kr[tile][1] = *(const bf16x8*)(bK + tile * 2048 + 1024 + lbo);
    }

    bool near = (k0 > qw - 192) && (k0 < qw + 160);
#pragma unroll
    for (int g = 0; g < 2; g++) {
      char* ps = myPs + g * 2048;
      floatx4 st[4];
#pragma unroll
      for (int tile = 0; tile < 4; tile++) {
        st[tile] = __builtin_amdgcn_mfma_f32_16x16x32_bf16(Kr[tile][0], Qf[g][0], zero, 0, 0, 0);
        st[tile] = __builtin_amdgcn_mfma_f32_16x16x32_bf16(Kr[tile][1], Qf[g][1], st[tile], 0, 0, 0);
      }
      if (near) {
#pragma unroll
        for (int tile = 0; tile < 4; tile++) {
          int bidx = k0 + tile * 16 + quad * 4 - (qw + g * 16 + ln) + 2048;
          float p0 = __builtin_amdgcn_exp2f(fmaf(st[tile][0], LOG2E, bt[bidx + 0]));
          float p1 = __builtin_amdgcn_exp2f(fmaf(st[tile][1], LOG2E, bt[bidx + 1]));
          float p2 = __builtin_amdgcn_exp2f(fmaf(st[tile][2], LOG2E, bt[bidx + 2]));
          float p3 = __builtin_amdgcn_exp2f(fmaf(st[tile][3], LOG2E, bt[bidx + 3]));
          l_acc[g] += (p0 + p1) + (p2 + p3);
          bf16x4 pk = {(__bf16)p0, (__bf16)p1, (__bf16)p2, (__bf16)p3};
          int chunk = tile * 2 + (quad >> 1);
          *(bf16x4*)(ps + (ln * 8 + (chunk ^ (ln & 7))) * 16 + (quad & 1) * 8) = pk;
        }
      } else {
        float cb = (k0 > qw) ? cpos : cneg;
#pragma unroll
        for (int tile = 0; tile < 4; tile++) {
          float p0 = __builtin_amdgcn_exp2f(fmaf(st[tile][0], LOG2E, cb));
          float p1 = __builtin_amdgcn_exp2f(fmaf(st[tile][1], LOG2E, cb));
          float p2 = __builtin_amdgcn_exp2f(fmaf(st[tile][2], LOG2E, cb));
          float p3 = __builtin_amdgcn_exp2f(fmaf(st[tile][3], LOG2E, cb));
          l_acc[g] += (p0 + p1) + (p2 + p3);
          bf16x4 pk = {(__bf16)p0, (__bf16)p1, (__bf16)p2, (__bf16)p3};
          int chunk = tile * 2 + (quad >> 1);
          *(bf16x4*)(ps + (ln * 8 + (chunk ^ (ln & 7))) * 16 + (quad & 1) * 8) = pk;
        }
      }
    }

    // PV: A = P from per-wave LDS, B = V (prefetched registers)
#pragma unroll
    for (int g = 0; g < 2; g++) {
      char* ps = myPs + g * 2048;
      bf16x8 Pf0 = *(const bf16x8*)(ps + (ln * 8 + (quad ^ (ln & 7))) * 16);
      bf16x8 Pf1 = *(const bf16x8*)(ps + (ln * 8 + ((4 + quad) ^ (ln & 7))) * 16);
#pragma unroll
      for (int dt = 0; dt < 4; dt++) {
        o[g][dt] = __builtin_amdgcn_mfma_f32_16x16x32_bf16(Pf0, Vc[dt][0], o[g][dt], 0, 0, 0);
        o[g][dt] = __builtin_amdgcn_mfma_f32_16x16x32_bf16(Pf1, Vc[dt][1], o[g][dt], 0, 0, 0);
      }
    }

    if (kn < S_) {
#pragma unroll
      for (int dt = 0; dt < 4; dt++) {
        Vc[dt][0] = Vn[dt][0]; Vc[dt][1] = Vn[dt][1];
      }
    }
    pb ^= 1;
  }

  // final l reduction across quads, then scale+store
#pragma unroll
  for (int g = 0; g < 2; g++) {
    l_acc[g] += __shfl_xor(l_acc[g], 16);
    l_acc[g] += __shfl_xor(l_acc[g], 32);
  }
#pragma unroll
  for (int g = 0; g < 2; g++)
#pragma unroll
    for (int rr = 0; rr < 4; rr++) {
      float linv = 1.0f / __shfl(l_acc[g], quad * 4 + rr);
      int q = qw + g * 16 + quad * 4 + rr;
#pragma unroll
      for (int dt = 0; dt < 4; dt++)
        ctx[(long)(b * S_ + q) * 1024 + h * 64 + dt * 16 + ln] =
            __float2bfloat16(o[g][dt][rr] * linv);
    }
}

// ---------------------------------------------------------------------------
// Out-proj GEMM: C[M][N] = A[M][K] * Bt[N][K]^T (fp32 out), m97-style staging.
// ---------------------------------------------------------------------------
__global__ __launch_bounds__(256) void gemm_bt_kernel(const bf16* __restrict__ A,
                                                      const bf16* __restrict__ Bt,
                                                      float* __restrict__ C,
                                                      int M, int N, int K) {
  __shared__ bf16 As[128 * 32];
  __shared__ bf16 Bs[128 * 32];
  int t = threadIdx.x;
  int m0 = blockIdx.y * 128, n0 = blockIdx.x * 128;
  int w = t >> 6, lane = t & 63, ln = lane & 15, quad = lane >> 4;
  int wr = w >> 1, wc = w & 1;
  floatx4 acc[4][4];
  floatx4 zero = {0.f, 0.f, 0.f, 0.f};
#pragma unroll
  for (int i = 0; i < 4; i++)
#pragma unroll
    for (int j = 0; j < 4; j++) acc[i][j] = zero;

  int r = t >> 2, c = (t & 3) * 8;
  const bf16* Ag = A + (long)(m0 + r) * K + c;
  const bf16* Bg = Bt + (long)(n0 + r) * K + c;
  char* ldsA0 = (char*)As + w * 1024;
  char* ldsA1 = ldsA0 + 4096;
  char* ldsB0 = (char*)Bs + w * 1024;
  char* ldsB1 = ldsB0 + 4096;

  for (int k0 = 0; k0 < K; k0 += 32) {
    load_lds16(Ag + k0, ldsA0);
    load_lds16(Ag + (long)64 * K + k0, ldsA1);
    load_lds16(Bg + k0, ldsB0);
    load_lds16(Bg + (long)64 * K + k0, ldsB1);
    __syncthreads();
    bf16x8 af[4], bfv[4];
#pragma unroll
    for (int i = 0; i < 4; i++)
      af[i] = *(const bf16x8*)&As[(wr * 64 + i * 16 + ln) * 32 + quad * 8];
#pragma unroll
    for (int j = 0; j < 4; j++)
      bfv[j] = *(const bf16x8*)&Bs[(wc * 64 + j * 16 + ln) * 32 + quad * 8];
#pragma unroll
    for (int i = 0; i < 4; i++)
#pragma unroll
      for (int j = 0; j < 4; j++)
        acc[i][j] = __builtin_amdgcn_mfma_f32_16x16x32_bf16(af[i], bfv[j], acc[i][j], 0, 0, 0);
    __syncthreads();
  }

#pragma unroll
  for (int i = 0; i < 4; i++)
#pragma unroll
    for (int j = 0; j < 4; j++)
#pragma unroll
      for (int rr = 0; rr < 4; rr++)
        C[(long)(m0 + wr * 64 + i * 16 + quad * 4 + rr) * N + n0 + wc * 64 + j * 16 + ln] =
            acc[i][j][rr];
}

// ---------------------------------------------------------------------------
extern "C" void kernel_launch(void* const* d_in, const int* in_sizes, int n_in,
                              void* d_out, int out_size, void* d_ws, size_t ws_size,
                              hipStream_t stream) {
  (void)in_sizes; (void)n_in; (void)out_size; (void)ws_size;
  const float* hidden   = (const float*)d_in[0];
  const float* Wq       = (const float*)d_in[1];
  const float* Wk       = (const float*)d_in[2];
  const float* Wv       = (const float*)d_in[3];
  const float* Wo       = (const float*)d_in[4];
  const float* rel_bias = (const float*)d_in[5];

  char* ws = (char*)d_ws;
  bf16*  hbf    = (bf16*)(ws + 0);                 //  8 MB [4096][1024]
  bf16*  wt_qkv = (bf16*)(ws + 8388608);           //  6 MB
  bf16*  wt_o   = (bf16*)(ws + 14680064);          //  2 MB
  float* btab   = (float*)(ws + 16777216);         // 256 KB
  bf16*  qh     = (bf16*)(ws + 17039360);          //  8 MB head-major Q
  bf16*  kf     = (bf16*)(ws + 25427968);          //  8 MB frag-major K
  bf16*  vf     = (bf16*)(ws + 33816576);          //  8 MB frag-major V
  bf16*  ctx    = (bf16*)(ws + 42205184);          //  8 MB

  cast_f32_bf16_kernel<<<dim3(4096), dim3(256), 0, stream>>>(hidden, hbf);
  transpose_w_kernel<<<dim3(32, 32, 4), dim3(32, 8), 0, stream>>>(Wq, Wk, Wv, Wo, wt_qkv, wt_o);
  bias_table_kernel<<<dim3(256), dim3(256), 0, stream>>>(rel_bias, btab);
  gemm_qkv_kernel<<<dim3(24, 32), dim3(256), 0, stream>>>(hbf, wt_qkv, qh, kf, vf);
  attn_kernel<<<dim3(32, 16), dim3(256), 0, stream>>>(qh, kf, vf, btab, ctx);
  gemm_bt_kernel<<<dim3(8, 32), dim3(256), 0, stream>>>(ctx, wt_o, (float*)d_out, 4096, 1024, 1024);
}

// Round 10
// 206.367 us; speedup vs baseline: 1.0012x; 1.0012x over previous
//
#include <hip/hip_runtime.h>
#include <hip/hip_bf16.h>

typedef __bf16 bf16x8 __attribute__((ext_vector_type(8)));
typedef __bf16 bf16x4 __attribute__((ext_vector_type(4)));
typedef float floatx4 __attribute__((ext_vector_type(4)));
using bf16 = __hip_bfloat16;

#define S_    2048
#define NHEAD 16
#define LOG2E 1.4426950408889634f

// Async global->LDS DMA, 16 B per lane (lane i -> lds + i*16).
__device__ __forceinline__ void load_lds16(const bf16* g, void* lds) {
  __builtin_amdgcn_global_load_lds((const __attribute__((address_space(1))) void*)g,
                                   (__attribute__((address_space(3))) void*)lds, 16, 0, 0);
}

// ---------------------------------------------------------------------------
// Fused preprocessing: [0,2048) cast hidden fp32->bf16 (8 elem/thread);
// [2048,6144) weight transpose+cast; [6144,6400) bias LUT (pre-scaled log2e).
// ---------------------------------------------------------------------------
__global__ void prep_kernel(const float* __restrict__ hidden,
                            const float* __restrict__ wq, const float* __restrict__ wk,
                            const float* __restrict__ wv, const float* __restrict__ wo,
                            const float* __restrict__ rel_bias,
                            bf16* __restrict__ hbf, bf16* __restrict__ wt_qkv,
                            bf16* __restrict__ wt_o, float* __restrict__ btab) {
  __shared__ bf16 tile[32][33];
  int bx = blockIdx.x, t = threadIdx.x;
  if (bx < 2048) {                             // cast: 8 elems/thread
    int i = (bx * 256 + t) * 8;
    float4 v0 = *(const float4*)(hidden + i);
    float4 v1 = *(const float4*)(hidden + i + 4);
    bf16 o8[8] = {__float2bfloat16(v0.x), __float2bfloat16(v0.y),
                  __float2bfloat16(v0.z), __float2bfloat16(v0.w),
                  __float2bfloat16(v1.x), __float2bfloat16(v1.y),
                  __float2bfloat16(v1.z), __float2bfloat16(v1.w)};
    *(uint4*)(hbf + i) = *(const uint4*)o8;
  } else if (bx < 6144) {                      // weight transpose
    int mat = (bx - 2048) >> 10, tb = (bx - 2048) & 1023;
    int n0 = (tb & 31) * 32, k0 = (tb >> 5) * 32;
    const float* src = (mat == 0) ? wq : (mat == 1) ? wk : (mat == 2) ? wv : wo;
    bf16* dst = (mat == 3) ? wt_o : wt_qkv + mat * 1024 * 1024;
    int tx = t & 31, ty = t >> 5;
#pragma unroll
    for (int j = 0; j < 32; j += 8)
      tile[ty + j][tx] = __float2bfloat16(src[(k0 + ty + j) * 1024 + n0 + tx]);
    __syncthreads();
#pragma unroll
    for (int j = 0; j < 32; j += 8)
      dst[(n0 + ty + j) * 1024 + k0 + tx] = tile[tx][ty + j];
  } else {                                     // bias LUT
    int idx = (bx - 6144) * 256 + t;           // 65536
    int h = idx >> 12, j = idx & 4095;
    int delta = j - 2048;
    int rb = (delta > 0) ? 16 : 0;
    int rpa = delta < 0 ? -delta : delta;
    int bsmall;
    if (rpa < 8) {
      bsmall = rpa;
    } else {
      int lg = 25 - __clz(rpa * rpa);
      bsmall = 8 + lg;
      if (bsmall > 15) bsmall = 15;
    }
    btab[idx] = rel_bias[(rb + bsmall) * 16 + h] * LOG2E;
  }
}

// ---------------------------------------------------------------------------
// QKV GEMM, m97-style staging. Epilogue writes q head-major (qh[bh][s][64])
// and K/V directly in MFMA-fragment-major layouts (kf/vf).
// ---------------------------------------------------------------------------
__global__ __launch_bounds__(256) void gemm_qkv_kernel(const bf16* __restrict__ A,
                                                       const bf16* __restrict__ Bt,
                                                       bf16* __restrict__ qh,
                                                       bf16* __restrict__ kf,
                                                       bf16* __restrict__ vf) {
  const int K = 1024;
  __shared__ bf16 As[128 * 32];
  __shared__ bf16 Bs[128 * 32];
  int t = threadIdx.x;
  int m0 = blockIdx.y * 128, n0 = blockIdx.x * 128;
  int w = t >> 6, lane = t & 63, ln = lane & 15, quad = lane >> 4;
  int wr = w >> 1, wc = w & 1;
  floatx4 acc[4][4];
  floatx4 zero = {0.f, 0.f, 0.f, 0.f};
#pragma unroll
  for (int i = 0; i < 4; i++)
#pragma unroll
    for (int j = 0; j < 4; j++) acc[i][j] = zero;

  int r = t >> 2, c = (t & 3) * 8;
  const bf16* Ag = A + (long)(m0 + r) * K + c;
  const bf16* Bg = Bt + (long)(n0 + r) * K + c;
  char* ldsA0 = (char*)As + w * 1024;
  char* ldsA1 = ldsA0 + 4096;
  char* ldsB0 = (char*)Bs + w * 1024;
  char* ldsB1 = ldsB0 + 4096;

  for (int k0 = 0; k0 < K; k0 += 32) {
    load_lds16(Ag + k0, ldsA0);
    load_lds16(Ag + (long)64 * K + k0, ldsA1);
    load_lds16(Bg + k0, ldsB0);
    load_lds16(Bg + (long)64 * K + k0, ldsB1);
    __syncthreads();
    bf16x8 af[4], bfv[4];
#pragma unroll
    for (int i = 0; i < 4; i++)
      af[i] = *(const bf16x8*)&As[(wr * 64 + i * 16 + ln) * 32 + quad * 8];
#pragma unroll
    for (int j = 0; j < 4; j++)
      bfv[j] = *(const bf16x8*)&Bs[(wc * 64 + j * 16 + ln) * 32 + quad * 8];
#pragma unroll
    for (int i = 0; i < 4; i++)
#pragma unroll
      for (int j = 0; j < 4; j++)
        acc[i][j] = __builtin_amdgcn_mfma_f32_16x16x32_bf16(af[i], bfv[j], acc[i][j], 0, 0, 0);
    __syncthreads();
  }

  int nb = n0 + wc * 64;
  int type = nb >> 10, h = (nb >> 6) & 15;
  int b = (m0 >> 11);
  int sl0 = (m0 & 2047) + wr * 64;
  long bhbase = (long)((b * 16 + h)) * 131072;

  if (type == 0) {
#pragma unroll
    for (int i = 0; i < 4; i++)
#pragma unroll
      for (int j = 0; j < 4; j++) {
        int d = j * 16 + ln;
#pragma unroll
        for (int rr = 0; rr < 4; rr++) {
          int s = sl0 + i * 16 + quad * 4 + rr;
          qh[bhbase + (long)s * 64 + d] = __float2bfloat16(acc[i][j][rr]);
        }
      }
  } else if (type == 1) {
#pragma unroll
    for (int i = 0; i < 4; i++)
#pragma unroll
      for (int j = 0; j < 4; j++) {
        int d = j * 16 + ln;
        int dpart = (d >> 5) * 512 + ((d >> 3) & 3) * 128 + (d & 7);
        int kb = (sl0 + i * 16) * 64;
#pragma unroll
        for (int rr = 0; rr < 4; rr++)
          kf[bhbase + kb + dpart + (quad * 4 + rr) * 8] = __float2bfloat16(acc[i][j][rr]);
      }
  } else {
#pragma unroll
    for (int i = 0; i < 4; i++)
#pragma unroll
      for (int j = 0; j < 4; j++) {
        int off = (sl0 + (i >> 1) * 32) * 64 + j * 512 +
                  ((quad >> 1) + ((i & 1) << 1)) * 128 + ln * 8 + (quad & 1) * 4;
        bf16x4 pk = {(__bf16)acc[i][j][0], (__bf16)acc[i][j][1],
                     (__bf16)acc[i][j][2], (__bf16)acc[i][j][3]};
        *(bf16x4*)(vf + bhbase + off) = pk;
      }
  }
}

// ---------------------------------------------------------------------------
// Split-K flash attention. Grid (32 bh, 16 qblk, 2 ks) = 1024 blocks =
// 4 blocks/CU (16 waves/CU for cross-wave MFMA/VALU overlap). 4 waves x 32 q.
// Fixed-max softmax => k-split partials are PLAIN SUMS: each block writes
// fp32 partial o and l; reduce kernel combines. K+V LDS double-buffered
// (16KB x2), single per-wave 2KB P buffer reused across both q-groups.
// LDS = 32KB KV + 8KB P = 40960 B -> exactly 4 blocks/CU.
// ---------------------------------------------------------------------------
__global__ __launch_bounds__(256, 2) void attn_kernel(const bf16* __restrict__ qh,
                                                      const bf16* __restrict__ kf,
                                                      const bf16* __restrict__ vf,
                                                      const float* __restrict__ btab,
                                                      float* __restrict__ opart,
                                                      float* __restrict__ lpart) {
  __shared__ char KV[2][16384];                // [buf][K 8KB | V 8KB]
  __shared__ char PsRaw[4 * 2048];             // per-wave 2KB P (reused per g)
  int t = threadIdx.x, w = t >> 6, lane = t & 63, ln = lane & 15, quad = lane >> 4;
  int bh = blockIdx.x, h = bh & 15;
  int qw = blockIdx.y * 128 + w * 32;          // this wave's first q row
  int ks = blockIdx.z, kbase0 = ks * 1024;

  const bf16* qbase = qh + (long)bh * S_ * 64;
  const bf16* kfb = kf + (long)bh * S_ * 64 + (long)kbase0 * 64;
  const bf16* vfb = vf + (long)bh * S_ * 64 + (long)kbase0 * 64;
  const float* bt = btab + h * 4096;
  char* myPs = PsRaw + w * 2048;
  int lbo = quad * 256 + ln * 16;              // lane byte offset inside 1KB frag

  // Q as B-operand: lane holds q = qw+g*16+ln, d = f*32+quad*8+j
  bf16x8 Qf[2][2];
#pragma unroll
  for (int g = 0; g < 2; g++) {
    const bf16* qr = qbase + (long)(qw + g * 16 + ln) * 64;
    Qf[g][0] = *(const bf16x8*)(qr + quad * 8);
    Qf[g][1] = *(const bf16x8*)(qr + 32 + quad * 8);
  }

  float cneg = bt[0], cpos = bt[4095];
  float l_acc[2] = {0.f, 0.f};
  floatx4 o[2][4];
  floatx4 zero = {0.f, 0.f, 0.f, 0.f};
#pragma unroll
  for (int g = 0; g < 2; g++)
#pragma unroll
    for (int dt = 0; dt < 4; dt++) o[g][dt] = zero;

  // stage tile 0 into buf 0 (thread t moves 16B of each 8KB region)
  load_lds16(kfb + t * 8, KV[0] + w * 1024);
  load_lds16(kfb + 2048 + t * 8, KV[0] + 4096 + w * 1024);
  load_lds16(vfb + t * 8, KV[0] + 8192 + w * 1024);
  load_lds16(vfb + 2048 + t * 8, KV[0] + 12288 + w * 1024);

  int pb = 0;
  for (int it = 0; it < 16; it++) {
    int k0 = kbase0 + it * 64;
    __syncthreads();                           // buf pb DMA done; prev reads done
    if (it < 15) {                             // issue next tile's DMA
      const bf16* kg = kfb + (it + 1) * 4096 + t * 8;   // 64 k * 64 d
      const bf16* vg = vfb + (it + 1) * 4096 + t * 8;
      char* nb_ = KV[pb ^ 1];
      load_lds16(kg, nb_ + w * 1024);
      load_lds16(kg + 2048, nb_ + 4096 + w * 1024);
      load_lds16(vg, nb_ + 8192 + w * 1024);
      load_lds16(vg + 2048, nb_ + 12288 + w * 1024);
    }

    const char* bK = KV[pb];
    const char* bV = KV[pb] + 8192;
    bf16x8 Kr[4][2], Vr[4][2];
#pragma unroll
    for (int tile = 0; tile < 4; tile++) {
      Kr[tile][0] = *(const bf16x8*)(bK + tile * 2048 + lbo);
      Kr[tile][1] = *(const bf16x8*)(bK + tile * 2048 + 1024 + lbo);
    }
#pragma unroll
    for (int f = 0; f < 2; f++)
#pragma unroll
      for (int dt = 0; dt < 4; dt++)
        Vr[dt][f] = *(const bf16x8*)(bV + f * 4096 + dt * 1024 + lbo);

    bool near = (k0 > qw - 192) && (k0 < qw + 160);
#pragma unroll
    for (int g = 0; g < 2; g++) {
      floatx4 st[4];
#pragma unroll
      for (int tile = 0; tile < 4; tile++) {
        st[tile] = __builtin_amdgcn_mfma_f32_16x16x32_bf16(Kr[tile][0], Qf[g][0], zero, 0, 0, 0);
        st[tile] = __builtin_amdgcn_mfma_f32_16x16x32_bf16(Kr[tile][1], Qf[g][1], st[tile], 0, 0, 0);
      }
      if (near) {
#pragma unroll
        for (int tile = 0; tile < 4; tile++) {
          int bidx = k0 + tile * 16 + quad * 4 - (qw + g * 16 + ln) + 2048;
          float p0 = __builtin_amdgcn_exp2f(fmaf(st[tile][0], LOG2E, bt[bidx + 0]));
          float p1 = __builtin_amdgcn_exp2f(fmaf(st[tile][1], LOG2E, bt[bidx + 1]));
          float p2 = __builtin_amdgcn_exp2f(fmaf(st[tile][2], LOG2E, bt[bidx + 2]));
          float p3 = __builtin_amdgcn_exp2f(fmaf(st[tile][3], LOG2E, bt[bidx + 3]));
          l_acc[g] += (p0 + p1) + (p2 + p3);
          bf16x4 pk = {(__bf16)p0, (__bf16)p1, (__bf16)p2, (__bf16)p3};
          int chunk = tile * 2 + (quad >> 1);
          *(bf16x4*)(myPs + (ln * 8 + (chunk ^ (ln & 7))) * 16 + (quad & 1) * 8) = pk;
        }
      } else {
        float cb = (k0 > qw) ? cpos : cneg;
#pragma unroll
        for (int tile = 0; tile < 4; tile++) {
          float p0 = __builtin_amdgcn_exp2f(fmaf(st[tile][0], LOG2E, cb));
          float p1 = __builtin_amdgcn_exp2f(fmaf(st[tile][1], LOG2E, cb));
          float p2 = __builtin_amdgcn_exp2f(fmaf(st[tile][2], LOG2E, cb));
          float p3 = __builtin_amdgcn_exp2f(fmaf(st[tile][3], LOG2E, cb));
          l_acc[g] += (p0 + p1) + (p2 + p3);
          bf16x4 pk = {(__bf16)p0, (__bf16)p1, (__bf16)p2, (__bf16)p3};
          int chunk = tile * 2 + (quad >> 1);
          *(bf16x4*)(myPs + (ln * 8 + (chunk ^ (ln & 7))) * 16 + (quad & 1) * 8) = pk;
        }
      }

      // PV for this group (P buffer reused; same-wave DS ordering is safe)
      bf16x8 Pf0 = *(const bf16x8*)(myPs + (ln * 8 + (quad ^ (ln & 7))) * 16);
      bf16x8 Pf1 = *(const bf16x8*)(myPs + (ln * 8 + ((4 + quad) ^ (ln & 7))) * 16);
#pragma unroll
      for (int dt = 0; dt < 4; dt++) {
        o[g][dt] = __builtin_amdgcn_mfma_f32_16x16x32_bf16(Pf0, Vr[dt][0], o[g][dt], 0, 0, 0);
        o[g][dt] = __builtin_amdgcn_mfma_f32_16x16x32_bf16(Pf1, Vr[dt][1], o[g][dt], 0, 0, 0);
      }
    }
    pb ^= 1;
  }

  // reduce l across quads; write fp32 partials (no division here)
  long obase = ((long)(ks * 32 + bh)) * S_ * 64;
#pragma unroll
  for (int g = 0; g < 2; g++) {
    l_acc[g] += __shfl_xor(l_acc[g], 16);
    l_acc[g] += __shfl_xor(l_acc[g], 32);
    if (quad == 0)
      lpart[(long)(ks * 32 + bh) * S_ + qw + g * 16 + ln] = l_acc[g];
#pragma unroll
    for (int rr = 0; rr < 4; rr++) {
      int q = qw + g * 16 + quad * 4 + rr;
#pragma unroll
      for (int dt = 0; dt < 4; dt++)
        opart[obase + (long)q * 64 + dt * 16 + ln] = o[g][dt][rr];
    }
  }
}

// ---------------------------------------------------------------------------
// Split-K reduce: ctx = (o0 + o1) / (l0 + l1), bf16 out. 4 floats/thread.
// ---------------------------------------------------------------------------
__global__ void reduce_kernel(const float* __restrict__ opart,
                              const float* __restrict__ lpart,
                              bf16* __restrict__ ctx) {
  long flat = ((long)blockIdx.x * 256 + threadIdx.x) * 4;
  int d = flat & 63;
  int q = (int)((flat >> 6) & 2047);
  int bh = (int)(flat >> 17);
  long base = ((long)bh * S_ + q) * 64 + d;
  float4 o0 = *(const float4*)(opart + base);
  float4 o1 = *(const float4*)(opart + 4194304 + base);
  float inv = 1.0f / (lpart[(long)bh * S_ + q] + lpart[65536 + (long)bh * S_ + q]);
  bf16x4 pk = {(__bf16)((o0.x + o1.x) * inv), (__bf16)((o0.y + o1.y) * inv),
               (__bf16)((o0.z + o1.z) * inv), (__bf16)((o0.w + o1.w) * inv)};
  *(bf16x4*)(ctx + ((long)((bh >> 4) * S_ + q)) * 1024 + (bh & 15) * 64 + d) = pk;
}

// ---------------------------------------------------------------------------
// Out-proj GEMM: C[M][N] = A[M][K] * Bt[N][K]^T (fp32 out), m97-style staging.
// ---------------------------------------------------------------------------
__global__ __launch_bounds__(256) void gemm_bt_kernel(const bf16* __restrict__ A,
                                                      const bf16* __restrict__ Bt,
                                                      float* __restrict__ C,
                                                      int M, int N, int K) {
  __shared__ bf16 As[128 * 32];
  __shared__ bf16 Bs[128 * 32];
  int t = threadIdx.x;
  int m0 = blockIdx.y * 128, n0 = blockIdx.x * 128;
  int w = t >> 6, lane = t & 63, ln = lane & 15, quad = lane >> 4;
  int wr = w >> 1, wc = w & 1;
  floatx4 acc[4][4];
  floatx4 zero = {0.f, 0.f, 0.f, 0.f};
#pragma unroll
  for (int i = 0; i < 4; i++)
#pragma unroll
    for (int j = 0; j < 4; j++) acc[i][j] = zero;

  int r = t >> 2, c = (t & 3) * 8;
  const bf16* Ag = A + (long)(m0 + r) * K + c;
  const bf16* Bg = Bt + (long)(n0 + r) * K + c;
  char* ldsA0 = (char*)As + w * 1024;
  char* ldsA1 = ldsA0 + 4096;
  char* ldsB0 = (char*)Bs + w * 1024;
  char* ldsB1 = ldsB0 + 4096;

  for (int k0 = 0; k0 < K; k0 += 32) {
    load_lds16(Ag + k0, ldsA0);
    load_lds16(Ag + (long)64 * K + k0, ldsA1);
    load_lds16(Bg + k0, ldsB0);
    load_lds16(Bg + (long)64 * K + k0, ldsB1);
    __syncthreads();
    bf16x8 af[4], bfv[4];
#pragma unroll
    for (int i = 0; i < 4; i++)
      af[i] = *(const bf16x8*)&As[(wr * 64 + i * 16 + ln) * 32 + quad * 8];
#pragma unroll
    for (int j = 0; j < 4; j++)
      bfv[j] = *(const bf16x8*)&Bs[(wc * 64 + j * 16 + ln) * 32 + quad * 8];
#pragma unroll
    for (int i = 0; i < 4; i++)
#pragma unroll
      for (int j = 0; j < 4; j++)
        acc[i][j] = __builtin_amdgcn_mfma_f32_16x16x32_bf16(af[i], bfv[j], acc[i][j], 0, 0, 0);
    __syncthreads();
  }

#pragma unroll
  for (int i = 0; i < 4; i++)
#pragma unroll
    for (int j = 0; j < 4; j++)
#pragma unroll
      for (int rr = 0; rr < 4; rr++)
        C[(long)(m0 + wr * 64 + i * 16 + quad * 4 + rr) * N + n0 + wc * 64 + j * 16 + ln] =
            acc[i][j][rr];
}

// ---------------------------------------------------------------------------
extern "C" void kernel_launch(void* const* d_in, const int* in_sizes, int n_in,
                              void* d_out, int out_size, void* d_ws, size_t ws_size,
                              hipStream_t stream) {
  (void)in_sizes; (void)n_in; (void)out_size; (void)ws_size;
  const float* hidden   = (const float*)d_in[0];
  const float* Wq       = (const float*)d_in[1];
  const float* Wk       = (const float*)d_in[2];
  const float* Wv       = (const float*)d_in[3];
  const float* Wo       = (const float*)d_in[4];
  const float* rel_bias = (const float*)d_in[5];

  char* ws = (char*)d_ws;
  bf16*  hbf    = (bf16*)(ws + 0);                 //  8 MB [4096][1024]
  bf16*  wt_qkv = (bf16*)(ws + 8388608);           //  6 MB
  bf16*  wt_o   = (bf16*)(ws + 14680064);          //  2 MB
  float* btab   = (float*)(ws + 16777216);         // 256 KB
  bf16*  qh     = (bf16*)(ws + 17039360);          //  8 MB head-major Q
  bf16*  kf     = (bf16*)(ws + 25427968);          //  8 MB frag-major K
  bf16*  vf     = (bf16*)(ws + 33816576);          //  8 MB frag-major V
  bf16*  ctx    = (bf16*)(ws + 42205184);          //  8 MB
  float* opart  = (float*)(ws + 50593792);         // 32 MB fp32 partial o (2 splits)
  float* lpart  = (float*)(ws + 84148224);         // 512 KB fp32 partial l

  prep_kernel<<<dim3(6400), dim3(256), 0, stream>>>(hidden, Wq, Wk, Wv, Wo, rel_bias,
                                                    hbf, wt_qkv, wt_o, btab);
  gemm_qkv_kernel<<<dim3(24, 32), dim3(256), 0, stream>>>(hbf, wt_qkv, qh, kf, vf);
  attn_kernel<<<dim3(32, 16, 2), dim3(256), 0, stream>>>(qh, kf, vf, btab, opart, lpart);
  reduce_kernel<<<dim3(4096), dim3(256), 0, stream>>>(opart, lpart, ctx);
  gemm_bt_kernel<<<dim3(8, 32), dim3(256), 0, stream>>>(ctx, wt_o, (float*)d_out, 4096, 1024, 1024);
}